// Round 1
// baseline (664.177 us; speedup 1.0000x reference)
//
#include <hip/hip_runtime.h>
#include <math.h>

// Geometry constants
#define VIEWS 512
#define NDET 736
#define NX 256
#define NY 256
#define EXTENT 2
#define SINO_LEN (VIEWS * NDET)          // 376832
#define NVOX (NX * NY)                   // 65536
#define PER_VOX (VIEWS * EXTENT)         // 1024

// SCALE = (2*pi - 0) / (2 * VIEWS * EXTENT) = pi / 1024
__device__ __constant__ float kScale = (float)(M_PI / 1024.0);

// One wave (64 lanes) per voxel. Each lane handles 16 elements:
// 4 x int4 index loads + 4 x float4 weight loads (coalesced, 16B/lane),
// 16 scattered 4B gathers from x (1.47 MB -> L2 resident).
// Then a 6-step shuffle reduction; lane 0 writes the flipped output.
__global__ __launch_bounds__(256) void backproj_kernel(
    const float* __restrict__ x,      // [SINO_LEN]
    const float* __restrict__ weight, // [NVOX * PER_VOX]
    const float* __restrict__ bias,   // [NVOX]
    const int*   __restrict__ indices,// [NVOX * PER_VOX]
    float*       __restrict__ out)    // [NVOX]
{
    const int wave_in_block = threadIdx.x >> 6;
    const int lane          = threadIdx.x & 63;
    const int v             = blockIdx.x * 4 + wave_in_block; // voxel id
    const size_t base       = (size_t)v * PER_VOX;

    const int4*   ip = (const int4*)(indices + base);
    const float4* wp = (const float4*)(weight + base);

    float s = 0.0f;
#pragma unroll
    for (int k = 0; k < 4; ++k) {
        const int4   i4 = ip[lane + k * 64];
        const float4 w4 = wp[lane + k * 64];
        s += x[i4.x] * w4.x;
        s += x[i4.y] * w4.y;
        s += x[i4.z] * w4.z;
        s += x[i4.w] * w4.w;
    }

    // wave-64 reduction
#pragma unroll
    for (int off = 32; off > 0; off >>= 1)
        s += __shfl_down(s, off, 64);

    if (lane == 0) {
        // flip over both spatial axes: flattened index reversal
        out[NVOX - 1 - v] = bias[v] + kScale * s;
    }
}

extern "C" void kernel_launch(void* const* d_in, const int* in_sizes, int n_in,
                              void* d_out, int out_size, void* d_ws, size_t ws_size,
                              hipStream_t stream) {
    const float* x       = (const float*)d_in[0];
    const float* weight  = (const float*)d_in[1];
    const float* bias    = (const float*)d_in[2];
    const int*   indices = (const int*)d_in[3];
    float*       out     = (float*)d_out;

    // 4 waves per block, 1 voxel per wave
    const int blocks = NVOX / 4; // 16384
    backproj_kernel<<<blocks, 256, 0, stream>>>(x, weight, bias, indices, out);
}